// Round 21
// baseline (89.052 us; speedup 1.0000x reference)
//
#include <hip/hip_runtime.h>

typedef unsigned short u16;
typedef unsigned int   u32;
typedef u16   u16x8 __attribute__((ext_vector_type(8)));
typedef float f32x4 __attribute__((ext_vector_type(4)));
typedef float f32x16 __attribute__((ext_vector_type(16)));
typedef __bf16 bf16x8 __attribute__((ext_vector_type(8)));
typedef u32   u32x4 __attribute__((ext_vector_type(4)));

#define QSCALE  0.18033688011112f     // 0.125 * log2(e): scores in exp2 units
#define BM_OPEN  -28.8539008177793f   // -20 * log2(e)
#define BM_MASK  -14455.8043097f      // -(10000+20) * log2(e)

__device__ __forceinline__ u16 f2bf(float x){
  __bf16 h = (__bf16)x;
  return __builtin_bit_cast(u16, h);
}
__device__ __forceinline__ f32x16 mfma32(u16x8 a, u16x8 b, f32x16 c){
  return __builtin_amdgcn_mfma_f32_32x32x16_bf16(
      __builtin_bit_cast(bf16x8, a), __builtin_bit_cast(bf16x8, b), c, 0, 0, 0);
}
__device__ __forceinline__ void gld16(const void* g, void* l){
  __builtin_amdgcn_global_load_lds(
      (const __attribute__((address_space(1))) u32*)g,
      (__attribute__((address_space(3))) u32*)l, 16, 0, 0);
}
__device__ __forceinline__ u32 cvtpk(float lo, float hi){
  u32 d;
  asm("v_cvt_pk_bf16_f32 %0, %1, %2" : "=v"(d) : "v"(lo), "v"(hi));
  return d;
}
__device__ __forceinline__ void plswap(u32 &x, u32 &y){
  asm("v_permlane32_swap_b32 %0, %1" : "+v"(x), "+v"(y));
}

// ===================== layout (unchanged image) =====================
// Per (b,h,kt) tile: 8192 u16 = [K 4096 | V 4096], 16384 B.
//  K: K[key][d] bf16. Row=key, stride 64 u16 (128 B). chunk c at c ^ (key&7).
//  V: V^T[d][s] u32 (s,s+1)-pairs. Row=d, 32 u32. chunk c at c ^ (d&7).

// ===================== pre-pass: f32 KV -> swizzled bf16 tile image ==========
__global__ __launch_bounds__(256, 4)
void prepass(const float* __restrict__ KV, const int* __restrict__ MASK,
             u16* __restrict__ IMG, float* __restrict__ BIASM)
{
  const int tid = threadIdx.x;
  const int bid = blockIdx.x;        // ((b*16+h)*32 + kt)
  const int kt = bid & 31;
  const int h  = (bid >> 5) & 15;
  const int b  = bid >> 9;
  const int kb = kt*64;
  const size_t kv_b = (size_t)b*(2048u*2048u);
  u16* tile = IMG + (size_t)bid * 8192;

  {
    const int skey = tid >> 2, scp = tid & 3;
    const float* kp = KV + kv_b + (size_t)(kb + skey)*2048 + h*64 + 16*scp;
    f32x4 f0 = *(const f32x4*)(kp);
    f32x4 f1 = *(const f32x4*)(kp + 4);
    f32x4 f2 = *(const f32x4*)(kp + 8);
    f32x4 f3 = *(const f32x4*)(kp + 12);
    u16x8 c0, c1;
    #pragma unroll
    for (int e = 0; e < 4; ++e){
      c0[e] = f2bf(f0[e]); c0[e+4] = f2bf(f1[e]);
      c1[e] = f2bf(f2[e]); c1[e+4] = f2bf(f3[e]);
    }
    const int idx0 = skey*64 + (((2*scp) ^ (skey & 7)) << 3);
    *(u16x8*)&tile[idx0]     = c0;
    *(u16x8*)&tile[idx0 ^ 8] = c1;
  }
  {
    const int sdb = tid & 7, ssp = tid >> 3;
    const float* vp = KV + kv_b + (size_t)(kb + 2*ssp)*2048 + 1024 + h*64 + 8*sdb;
    f32x4 r0a = *(const f32x4*)(vp);
    f32x4 r0b = *(const f32x4*)(vp + 4);
    f32x4 r1a = *(const f32x4*)(vp + 2048);
    f32x4 r1b = *(const f32x4*)(vp + 2048 + 4);
    u32* vimg = (u32*)(tile + 4096);
    const int wc = ssp >> 2, wi = ssp & 3;
    #pragma unroll
    for (int j = 0; j < 4; ++j){
      const int d0 = 8*sdb + j;
      const int d1 = d0 + 4;
      vimg[d0*32 + ((wc ^ (d0 & 7)) << 2) + wi] = (u32)f2bf(r0a[j]) | ((u32)f2bf(r1a[j]) << 16);
      vimg[d1*32 + ((wc ^ (d1 & 7)) << 2) + wi] = (u32)f2bf(r0b[j]) | ((u32)f2bf(r1b[j]) << 16);
    }
  }
  if (h == 0 && tid < 64){
    const int s = kb + tid;
    BIASM[b*2048 + s] = MASK[b*2048 + s] ? BM_OPEN : BM_MASK;
  }
}

// ===================== main: 32x32 MFMA flash attention, 64 q/wave ===========
// Grid 512. Block = 2 waves x 64 q-rows = 128 rows (128 threads).
// Each wave: TWO q-streams (A,B) sharing every K/V fragment read -> LDS reads
// per q-row HALVED vs r16. r16's verified per-tile math; in-register P.
// Double-buffered DMA + plain __syncthreads (r12-proven). LDS 40960 B.
template<int PRE>
__global__ __launch_bounds__(128, 2)
void attn_main(const float* __restrict__ Q, const float* __restrict__ KV,
               const int* __restrict__ MASK, const u16* __restrict__ IMG,
               const float* __restrict__ BIASM, float* __restrict__ OUT)
{
  __shared__ __align__(16) u16 KVbuf[2][8192];   // 32 KB
  __shared__ __align__(16) float BiasLds[2048];  // 8 KB

  const int tid  = threadIdx.x;     // 0..127
  const int lane = tid & 63;
  const int hi   = lane >> 5;       // lane half
  const int lq   = lane & 31;       // q (and MFMA row) index
  const int w    = tid >> 6;        // wave 0/1

  const int bid0 = blockIdx.x;
  const int bid  = (bid0 & 7)*64 + (bid0 >> 3);   // XCD swizzle (bijective 8x64)
  const int qt  = bid & 15;
  const int h   = (bid >> 4) & 15;
  const int b   = bid >> 8;

  const int qA = qt*128 + w*64;     // stream A base
  const int qB = qA + 32;           // stream B base
  const size_t q_b  = (size_t)b * (2048u*1024u);
  const size_t kv_b = (size_t)b * (2048u*2048u);

  const int sw7 = lq & 7;

  // ---- Q fragments for both streams: lane holds Q[q=·+lq][d=16kc+8hi+e] ----
  u16x8 QfA[4], QfB[4];
  #pragma unroll
  for (int st = 0; st < 2; ++st){
    const int qrow = (st ? qB : qA) + lq;
    const float* qp = Q + q_b + (size_t)qrow*1024 + h*64 + 8*hi;
    #pragma unroll
    for (int kc = 0; kc < 4; ++kc){
      f32x4 a = *(const f32x4*)(qp + 16*kc);
      f32x4 c = *(const f32x4*)(qp + 16*kc + 4);
      u16x8 v;
      #pragma unroll
      for (int e = 0; e < 4; ++e){
        v[e]     = f2bf(a[e] * QSCALE);
        v[e + 4] = f2bf(c[e] * QSCALE);
      }
      if (st) QfB[kc] = v; else QfA[kc] = v;
    }
  }

  f32x16 OaA[2], OaB[2];
  #pragma unroll
  for (int dt = 0; dt < 2; ++dt)
    #pragma unroll
    for (int r = 0; r < 16; ++r){ OaA[dt][r] = 0.f; OaB[dt][r] = 0.f; }
  float lrunA = 0.f, lrunB = 0.f;

  // staging constants (128 threads: 8 x 16B per thread per tile)
  const char* img0 = (const char*)IMG + (size_t)((b*16 + h)*32) * 16384;
  const int so = tid*16;            // 0..2032

#define STAGE_ISSUE(T, DST) do{                                               \
    const char* g_ = img0 + (size_t)(T)*16384;                                \
    char* l_ = (char*)(DST);                                                  \
    _Pragma("unroll") for (int k_ = 0; k_ < 8; ++k_)                          \
      gld16(g_ + so + 2048*k_, l_ + so + 2048*k_);                            \
  }while(0)

#define BIAS_STAGE() do{                                                      \
    const char* gb_ = (const char*)BIASM + (size_t)b*8192;                    \
    char* lb_ = (char*)BiasLds;                                               \
    _Pragma("unroll") for (int k_ = 0; k_ < 4; ++k_)                          \
      gld16(gb_ + so + 2048*k_, lb_ + so + 2048*k_);                          \
  }while(0)

// SM: consumes SD -> PFD + LR (pure VALU/TRANS; r16-verified)
#define SM(SD, PFD, LR) do{                                                   \
    u32 pa[2][4], pb[2][4];                                                   \
    float ps = 0.f;                                                           \
    _Pragma("unroll") for (int ct = 0; ct < 2; ++ct){                         \
      _Pragma("unroll") for (int m = 0; m < 4; ++m){                          \
        const float p0 = __builtin_amdgcn_exp2f(SD[ct][4*m+0]);               \
        const float p1 = __builtin_amdgcn_exp2f(SD[ct][4*m+1]);               \
        const float p2 = __builtin_amdgcn_exp2f(SD[ct][4*m+2]);               \
        const float p3 = __builtin_amdgcn_exp2f(SD[ct][4*m+3]);               \
        ps += (p0 + p1) + (p2 + p3);                                          \
        pa[ct][m] = cvtpk(p0, p1);                                            \
        pb[ct][m] = cvtpk(p2, p3);                                            \
      }                                                                       \
    }                                                                         \
    LR += ps;                                                                 \
    _Pragma("unroll") for (int ct = 0; ct < 2; ++ct){                         \
      plswap(pa[ct][0], pa[ct][1]);  plswap(pb[ct][0], pb[ct][1]);            \
      plswap(pa[ct][2], pa[ct][3]);  plswap(pb[ct][2], pb[ct][3]);            \
      u32x4 f0_ = { pa[ct][0], pb[ct][0], pa[ct][1], pb[ct][1] };             \
      u32x4 f1_ = { pa[ct][2], pb[ct][2], pa[ct][3], pb[ct][3] };             \
      PFD[2*ct+0] = __builtin_bit_cast(u16x8, f0_);                           \
      PFD[2*ct+1] = __builtin_bit_cast(u16x8, f1_);                           \
    }                                                                         \
  }while(0)

// COMPUTE: bias C-init (shared A/B); QK shared-read (8 reads, 16 MFMA);
// SM x2; PV shared-read (8 reads, 16 MFMA).
#define COMPUTE(T, CUR) do{                                                   \
    const u16* Kb_ = (CUR);                                                   \
    const u32* vimg_ = (const u32*)((CUR) + 4096);                            \
    f32x16 SA[2], SB[2];                                                      \
    _Pragma("unroll") for (int ct = 0; ct < 2; ++ct){                         \
      _Pragma("unroll") for (int m = 0; m < 4; ++m){                          \
        f32x4 bq;                                                             \
        if constexpr (PRE){                                                   \
          bq = *(const f32x4*)&BiasLds[(T)*64 + 32*ct + 8*m + 4*hi];          \
        } else {                                                              \
          const int4 mv = *(const int4*)(MASK + b*2048 + (T)*64 + 32*ct + 8*m + 4*hi); \
          bq[0] = mv.x ? BM_OPEN : BM_MASK;                                   \
          bq[1] = mv.y ? BM_OPEN : BM_MASK;                                   \
          bq[2] = mv.z ? BM_OPEN : BM_MASK;                                   \
          bq[3] = mv.w ? BM_OPEN : BM_MASK;                                   \
        }                                                                     \
        SA[ct][4*m+0] = bq[0]; SA[ct][4*m+1] = bq[1];                         \
        SA[ct][4*m+2] = bq[2]; SA[ct][4*m+3] = bq[3];                         \
        SB[ct][4*m+0] = bq[0]; SB[ct][4*m+1] = bq[1];                         \
        SB[ct][4*m+2] = bq[2]; SB[ct][4*m+3] = bq[3];                         \
      }                                                                       \
    }                                                                         \
    __builtin_amdgcn_s_setprio(1);                                            \
    _Pragma("unroll") for (int ct = 0; ct < 2; ++ct){                         \
      _Pragma("unroll") for (int kc = 0; kc < 4; ++kc){                       \
        u16x8 kf = *(const u16x8*)&Kb_[(32*ct + lq)*64 + (((2*kc+hi)^sw7)<<3)]; \
        SA[ct] = mfma32(kf, QfA[kc], SA[ct]);                                 \
        SB[ct] = mfma32(kf, QfB[kc], SB[ct]);                                 \
      }                                                                       \
    }                                                                         \
    __builtin_amdgcn_s_setprio(0);                                            \
    u16x8 PfA[4], PfB[4];                                                     \
    SM(SA, PfA, lrunA);                                                       \
    SM(SB, PfB, lrunB);                                                       \
    __builtin_amdgcn_s_setprio(1);                                            \
    _Pragma("unroll") for (int dt = 0; dt < 2; ++dt){                         \
      _Pragma("unroll") for (int sc = 0; sc < 4; ++sc){                       \
        u32x4 vv = *(const u32x4*)&vimg_[(32*dt + lq)*32 + (((2*sc+hi)^sw7)<<2)]; \
        u16x8 vf = __builtin_bit_cast(u16x8, vv);                             \
        OaA[dt] = mfma32(vf, PfA[sc], OaA[dt]);                               \
        OaB[dt] = mfma32(vf, PfB[sc], OaB[dt]);                               \
      }                                                                       \
    }                                                                         \
    __builtin_amdgcn_s_setprio(0);                                            \
  }while(0)

  // ---- prologue ----
  if constexpr (PRE){
    BIAS_STAGE();
    STAGE_ISSUE(0, &KVbuf[0][0]);
  } else {
    // fallback staging: f32 -> bf16 convert in-kernel (128 threads)
    // K: row = tid>>1, half = tid&1 -> 4 chunks; V: 2 passes of r16 pattern.
    const int row_ = tid >> 1, half_ = tid & 1;
    const float* kp_ = KV + kv_b + (size_t)row_*2048 + h*64;
    #pragma unroll
    for (int cc = 0; cc < 4; ++cc){
      const int c_ = 4*half_ + cc;
      f32x4 fa = *(const f32x4*)(kp_ + 8*c_);
      f32x4 fb = *(const f32x4*)(kp_ + 8*c_ + 4);
      u16x8 cv;
      #pragma unroll
      for (int e = 0; e < 4; ++e){ cv[e] = f2bf(fa[e]); cv[e+4] = f2bf(fb[e]); }
      *(u16x8*)&KVbuf[0][row_*64 + ((c_ ^ (row_ & 7)) << 3)] = cv;
    }
    const int sdb_ = tid & 7, sp0_ = (tid >> 3) & 15;
    u32* vimg_ = (u32*)&KVbuf[0][4096];
    #pragma unroll
    for (int rep = 0; rep < 2; ++rep){
      const int ssp_ = sp0_ + 16*rep;
      const float* vp_ = KV + kv_b + (size_t)(2*ssp_)*2048 + 1024 + h*64 + 8*sdb_;
      f32x4 va = *(const f32x4*)(vp_);
      f32x4 vb2 = *(const f32x4*)(vp_ + 4);
      f32x4 vc = *(const f32x4*)(vp_ + 2048);
      f32x4 vd = *(const f32x4*)(vp_ + 2048 + 4);
      const int wc_ = ssp_ >> 2, wi_ = ssp_ & 3;
      #pragma unroll
      for (int j = 0; j < 4; ++j){
        const int d0_ = 8*sdb_ + j, d1_ = d0_ + 4;
        vimg_[d0_*32 + ((wc_ ^ (d0_&7)) << 2) + wi_] = (u32)f2bf(va[j])  | ((u32)f2bf(vc[j]) << 16);
        vimg_[d1_*32 + ((wc_ ^ (d1_&7)) << 2) + wi_] = (u32)f2bf(vb2[j]) | ((u32)f2bf(vd[j]) << 16);
      }
    }
  }
  __syncthreads();   // drains DMA (vmcnt) + joins waves

  // ---- main loop: double-buffer, stage t+1 while computing t ----
  for (int t = 0; t < 32; ++t){
    if constexpr (PRE){
      if (t < 31) STAGE_ISSUE(t+1, &KVbuf[(t+1) & 1][0]);
      COMPUTE(t, &KVbuf[t & 1][0]);
      if (t < 31) __syncthreads();
    } else {
      COMPUTE(t, &KVbuf[0][0]);
      if (t < 31){
        __syncthreads();
        // restage next tile (serial; fallback path, correctness only)
        const int kb_ = (t+1)*64;
        const int row_ = tid >> 1, half_ = tid & 1;
        const float* kp_ = KV + kv_b + (size_t)(kb_ + row_)*2048 + h*64;
        #pragma unroll
        for (int cc = 0; cc < 4; ++cc){
          const int c_ = 4*half_ + cc;
          f32x4 fa = *(const f32x4*)(kp_ + 8*c_);
          f32x4 fb = *(const f32x4*)(kp_ + 8*c_ + 4);
          u16x8 cv;
          #pragma unroll
          for (int e = 0; e < 4; ++e){ cv[e] = f2bf(fa[e]); cv[e+4] = f2bf(fb[e]); }
          *(u16x8*)&KVbuf[0][row_*64 + ((c_ ^ (row_ & 7)) << 3)] = cv;
        }
        const int sdb_ = tid & 7, sp0_ = (tid >> 3) & 15;
        u32* vimg_ = (u32*)&KVbuf[0][4096];
        #pragma unroll
        for (int rep = 0; rep < 2; ++rep){
          const int ssp_ = sp0_ + 16*rep;
          const float* vp_ = KV + kv_b + (size_t)(kb_ + 2*ssp_)*2048 + 1024 + h*64 + 8*sdb_;
          f32x4 va = *(const f32x4*)(vp_);
          f32x4 vb2 = *(const f32x4*)(vp_ + 4);
          f32x4 vc = *(const f32x4*)(vp_ + 2048);
          f32x4 vd = *(const f32x4*)(vp_ + 2048 + 4);
          const int wc_ = ssp_ >> 2, wi_ = ssp_ & 3;
          #pragma unroll
          for (int j = 0; j < 4; ++j){
            const int d0_ = 8*sdb_ + j, d1_ = d0_ + 4;
            vimg_[d0_*32 + ((wc_ ^ (d0_&7)) << 2) + wi_] = (u32)f2bf(va[j])  | ((u32)f2bf(vc[j]) << 16);
            vimg_[d1_*32 + ((wc_ ^ (d1_&7)) << 2) + wi_] = (u32)f2bf(vb2[j]) | ((u32)f2bf(vd[j]) << 16);
          }
        }
        __syncthreads();
      }
    }
  }

  // ---- epilogue: per stream, combine lane halves' l, normalize, store ----
  #pragma unroll
  for (int st = 0; st < 2; ++st){
    const float lr = st ? lrunB : lrunA;
    const float l_ = lr + __shfl_xor(lr, 32, 64);
    const float inv = 1.f / l_;
    const int qrow = (st ? qB : qA) + lq;
    float* op = OUT + q_b + (size_t)qrow*1024 + h*64;
    #pragma unroll
    for (int dt = 0; dt < 2; ++dt){
      #pragma unroll
      for (int m = 0; m < 4; ++m){
        f32x4 ov;
        const f32x16& Od = st ? OaB[dt] : OaA[dt];
        ov[0] = Od[4*m+0] * inv;
        ov[1] = Od[4*m+1] * inv;
        ov[2] = Od[4*m+2] * inv;
        ov[3] = Od[4*m+3] * inv;
        *(f32x4*)(op + 32*dt + 8*m + 4*hi) = ov;
      }
    }
  }
#undef STAGE_ISSUE
#undef BIAS_STAGE
#undef SM
#undef COMPUTE
}

extern "C" void kernel_launch(void* const* d_in, const int* in_sizes, int n_in,
                              void* d_out, int out_size, void* d_ws, size_t ws_size,
                              hipStream_t stream)
{
  const float* Q  = nullptr;
  const float* KV = nullptr;
  const int*   M  = nullptr;
  for (int i = 0; i < n_in; ++i){
    if      (in_sizes[i] == 4194304) Q  = (const float*)d_in[i];
    else if (in_sizes[i] == 8388608) KV = (const float*)d_in[i];
    else if (in_sizes[i] == 4096)    M  = (const int*)d_in[i];
  }
  if (!Q)  Q  = (const float*)d_in[0];
  if (!KV) KV = (const float*)d_in[1];
  if (!M)  M  = (const int*)d_in[2];
  float* O = (float*)d_out;

  const size_t NEED = 16384ull + 1024ull*16384ull;   // biasM + KV image (16.8 MB)
  if (ws_size >= NEED){
    float* biasm = (float*)d_ws;
    u16*   img   = (u16*)((char*)d_ws + 16384);
    prepass<<<dim3(1024), dim3(256), 0, stream>>>(KV, M, img, biasm);
    attn_main<1><<<dim3(512), dim3(128), 0, stream>>>(Q, KV, M, img, biasm, O);
  } else {
    attn_main<0><<<dim3(512), dim3(128), 0, stream>>>(Q, KV, M, nullptr, nullptr, O);
  }
}

// Round 22
// 69.410 us; speedup vs baseline: 1.2830x; 1.2830x over previous
//
#include <hip/hip_runtime.h>

typedef unsigned short u16;
typedef unsigned int   u32;
typedef u16   u16x8 __attribute__((ext_vector_type(8)));
typedef float f32x4 __attribute__((ext_vector_type(4)));
typedef float f32x16 __attribute__((ext_vector_type(16)));
typedef __bf16 bf16x8 __attribute__((ext_vector_type(8)));
typedef u32   u32x4 __attribute__((ext_vector_type(4)));

#define QSCALE  0.18033688011112f     // 0.125 * log2(e): scores in exp2 units
#define BM_OPEN  -28.8539008177793f   // -20 * log2(e)
#define BM_MASK  -14455.8043097f      // -(10000+20) * log2(e)

__device__ __forceinline__ u16 f2bf(float x){
  __bf16 h = (__bf16)x;
  return __builtin_bit_cast(u16, h);
}
__device__ __forceinline__ f32x16 mfma32(u16x8 a, u16x8 b, f32x16 c){
  return __builtin_amdgcn_mfma_f32_32x32x16_bf16(
      __builtin_bit_cast(bf16x8, a), __builtin_bit_cast(bf16x8, b), c, 0, 0, 0);
}
__device__ __forceinline__ void gld16(const void* g, void* l){
  __builtin_amdgcn_global_load_lds(
      (const __attribute__((address_space(1))) u32*)g,
      (__attribute__((address_space(3))) u32*)l, 16, 0, 0);
}
__device__ __forceinline__ u32 cvtpk(float lo, float hi){
  u32 d;
  asm("v_cvt_pk_bf16_f32 %0, %1, %2" : "=v"(d) : "v"(lo), "v"(hi));
  return d;
}
__device__ __forceinline__ void plswap(u32 &x, u32 &y){
  asm("v_permlane32_swap_b32 %0, %1" : "+v"(x), "+v"(y));
}

// ===================== layout (unchanged image) =====================
// Per (b,h,kt) tile: 8192 u16 = [K 4096 | V 4096], 16384 B.
//  K: K[key][d] bf16. Row=key, stride 64 u16 (128 B). chunk c at c ^ (key&7).
//  V: V^T[d][s] u32 (s,s+1)-pairs. Row=d, 32 u32. chunk c at c ^ (d&7).

// ===================== pre-pass: f32 KV -> swizzled bf16 tile image ==========
__global__ __launch_bounds__(256, 4)
void prepass(const float* __restrict__ KV, const int* __restrict__ MASK,
             u16* __restrict__ IMG, float* __restrict__ BIASM)
{
  const int tid = threadIdx.x;
  const int bid = blockIdx.x;        // ((b*16+h)*32 + kt)
  const int kt = bid & 31;
  const int h  = (bid >> 5) & 15;
  const int b  = bid >> 9;
  const int kb = kt*64;
  const size_t kv_b = (size_t)b*(2048u*2048u);
  u16* tile = IMG + (size_t)bid * 8192;

  {
    const int skey = tid >> 2, scp = tid & 3;
    const float* kp = KV + kv_b + (size_t)(kb + skey)*2048 + h*64 + 16*scp;
    f32x4 f0 = *(const f32x4*)(kp);
    f32x4 f1 = *(const f32x4*)(kp + 4);
    f32x4 f2 = *(const f32x4*)(kp + 8);
    f32x4 f3 = *(const f32x4*)(kp + 12);
    u16x8 c0, c1;
    #pragma unroll
    for (int e = 0; e < 4; ++e){
      c0[e] = f2bf(f0[e]); c0[e+4] = f2bf(f1[e]);
      c1[e] = f2bf(f2[e]); c1[e+4] = f2bf(f3[e]);
    }
    const int idx0 = skey*64 + (((2*scp) ^ (skey & 7)) << 3);
    *(u16x8*)&tile[idx0]     = c0;
    *(u16x8*)&tile[idx0 ^ 8] = c1;
  }
  {
    const int sdb = tid & 7, ssp = tid >> 3;
    const float* vp = KV + kv_b + (size_t)(kb + 2*ssp)*2048 + 1024 + h*64 + 8*sdb;
    f32x4 r0a = *(const f32x4*)(vp);
    f32x4 r0b = *(const f32x4*)(vp + 4);
    f32x4 r1a = *(const f32x4*)(vp + 2048);
    f32x4 r1b = *(const f32x4*)(vp + 2048 + 4);
    u32* vimg = (u32*)(tile + 4096);
    const int wc = ssp >> 2, wi = ssp & 3;
    #pragma unroll
    for (int j = 0; j < 4; ++j){
      const int d0 = 8*sdb + j;
      const int d1 = d0 + 4;
      vimg[d0*32 + ((wc ^ (d0 & 7)) << 2) + wi] = (u32)f2bf(r0a[j]) | ((u32)f2bf(r1a[j]) << 16);
      vimg[d1*32 + ((wc ^ (d1 & 7)) << 2) + wi] = (u32)f2bf(r0b[j]) | ((u32)f2bf(r1b[j]) << 16);
    }
  }
  if (h == 0 && tid < 64){
    const int s = kb + tid;
    BIASM[b*2048 + s] = MASK[b*2048 + s] ? BM_OPEN : BM_MASK;
  }
}

// ===================== main: 32x32 MFMA flash attention, KV-split ============
// PRE=1: grid 1024 = 16qt x 16h x 2b x 2half. Block = 4 waves x 32q = 128 rows,
//   LDS 40960 B -> 4 blocks/CU (exactly 160 KiB), 16 waves/CU from independent
//   phase-offset blocks. Each block computes KV tiles [half*16, half*16+16),
//   writes UNNORMALIZED O-partial + l-partial (fixed-shift => partials sum).
// PRE=0: grid 512 full 32 tiles, normalized OUT directly (r19 verbatim).
template<int PRE>
__global__ __launch_bounds__(256, 3)
void attn_main(const float* __restrict__ Q, const float* __restrict__ KV,
               const int* __restrict__ MASK, const u16* __restrict__ IMG,
               const float* __restrict__ BIASM, float* __restrict__ OP,
               float* __restrict__ LP, float* __restrict__ OUT)
{
  __shared__ __align__(16) u16 KVbuf[2][8192];   // 32 KB
  __shared__ __align__(16) float BiasLds[2048];  // 8 KB

  const int tid  = threadIdx.x;
  const int lane = tid & 63;
  const int hi   = lane >> 5;     // lane half
  const int lq   = lane & 31;     // q (and MFMA row) index

  const int bid0 = blockIdx.x;
  const int bid  = PRE ? ((bid0 & 7)*128 + (bid0 >> 3))     // grid 1024
                       : ((bid0 & 7)*64  + (bid0 >> 3));    // grid 512
  const int qt   = bid & 15;
  const int h    = (bid >> 4) & 15;
  const int b    = (bid >> 8) & 1;
  const int half = PRE ? (bid >> 9) : 0;
  const int t0   = half * 16;
  const int NT   = PRE ? 16 : 32;

  const int w    = tid >> 6;
  const int qbase = qt*128 + w*32;
  const size_t q_b  = (size_t)b * (2048u*1024u);
  const size_t kv_b = (size_t)b * (2048u*2048u);

  const int sw7 = lq & 7;

  // ---- Q fragments: lane holds Q[q=lq][d=16kc+8hi+e] ----
  u16x8 Qf[4];
  {
    const int qrow = qbase + lq;
    const float* qp = Q + q_b + (size_t)qrow*1024 + h*64 + 8*hi;
    #pragma unroll
    for (int kc = 0; kc < 4; ++kc){
      f32x4 a = *(const f32x4*)(qp + 16*kc);
      f32x4 c = *(const f32x4*)(qp + 16*kc + 4);
      u16x8 v;
      #pragma unroll
      for (int e = 0; e < 4; ++e){
        v[e]     = f2bf(a[e] * QSCALE);
        v[e + 4] = f2bf(c[e] * QSCALE);
      }
      Qf[kc] = v;
    }
  }

  f32x16 Oa[2];
  #pragma unroll
  for (int dt = 0; dt < 2; ++dt)
    #pragma unroll
    for (int r = 0; r < 16; ++r) Oa[dt][r] = 0.f;
  float lrun = 0.f;

  // staging constants
  const char* img0 = (const char*)IMG + (size_t)((b*16 + h)*32) * 16384;
  const int so = tid*16;
  const int skey = tid >> 2, scp = tid & 3;   // PRE=0 K
  const int sdb  = tid & 7,  ssp = tid >> 3;  // PRE=0 V
  const float* kp0 = KV + kv_b + (size_t)skey*2048 + h*64 + 16*scp;
  const float* vp0 = KV + kv_b + (size_t)(2*ssp)*2048 + 1024 + h*64 + 8*sdb;
  f32x4 kf0, kf1, kf2, kf3, va, vb2, vc, vd;   // PRE=0 staging regs

#define STAGE_ISSUE(T, DST) do{                                               \
    const char* g_ = img0 + (size_t)(T)*16384;                                \
    char* l_ = (char*)(DST);                                                  \
    gld16(g_+so,        l_+so);                                               \
    gld16(g_+so+4096,   l_+so+4096);                                          \
    gld16(g_+so+8192,   l_+so+8192);                                          \
    gld16(g_+so+12288,  l_+so+12288);                                         \
  }while(0)

#define BIAS_STAGE() do{                                                      \
    const char* gb_ = (const char*)BIASM + (size_t)b*8192;                    \
    char* lb_ = (char*)BiasLds;                                               \
    gld16(gb_+so,      lb_+so);                                               \
    gld16(gb_+so+4096, lb_+so+4096);                                          \
  }while(0)

#define STAGE_REG(T) do{                                                      \
    const float* kp_ = kp0 + (size_t)(T)*64*2048;                             \
    kf0=*(const f32x4*)(kp_);   kf1=*(const f32x4*)(kp_+4);                   \
    kf2=*(const f32x4*)(kp_+8); kf3=*(const f32x4*)(kp_+12);                  \
    const float* vp_ = vp0 + (size_t)(T)*64*2048;                             \
    va=*(const f32x4*)(vp_);      vb2=*(const f32x4*)(vp_+4);                 \
    vc=*(const f32x4*)(vp_+2048); vd =*(const f32x4*)(vp_+2048+4);            \
  }while(0)

#define STAGE_WRITE(DST) do{                                                  \
    u16x8 c0_, c1_;                                                           \
    _Pragma("unroll") for (int e_=0; e_<4; ++e_){                             \
      c0_[e_]=f2bf(kf0[e_]); c0_[e_+4]=f2bf(kf1[e_]);                         \
      c1_[e_]=f2bf(kf2[e_]); c1_[e_+4]=f2bf(kf3[e_]); }                       \
    const int kix_ = skey*64 + (((2*scp) ^ (skey & 7)) << 3);                 \
    *(u16x8*)&(DST)[kix_]     = c0_;                                          \
    *(u16x8*)&(DST)[kix_ ^ 8] = c1_;                                          \
    u32* vimg_ = (u32*)((DST)+4096);                                          \
    const int wc_ = ssp >> 2, wi_ = ssp & 3;                                  \
    _Pragma("unroll") for (int j_=0; j_<4; ++j_){                             \
      const int d0_=8*sdb+j_, d1_=d0_+4;                                      \
      vimg_[d0_*32 + ((wc_ ^ (d0_&7)) << 2) + wi_] = (u32)f2bf(va[j_])  | ((u32)f2bf(vc[j_])<<16); \
      vimg_[d1_*32 + ((wc_ ^ (d1_&7)) << 2) + wi_] = (u32)f2bf(vb2[j_]) | ((u32)f2bf(vd[j_])<<16); \
    }                                                                         \
  }while(0)

// r16/r19-verified COMPUTE: S C-init from bias; QK (8 MFMA); exp2; cvt_pk +
// permlane -> P frags in registers; PV (8 MFMA). No P LDS round-trip.
#define COMPUTE(T, CUR) do{                                                   \
    const u16* Kb_ = (CUR);                                                   \
    const u32* vimg_ = (const u32*)((CUR) + 4096);                            \
    f32x16 S[2];                                                              \
    _Pragma("unroll") for (int ct = 0; ct < 2; ++ct){                         \
      _Pragma("unroll") for (int m = 0; m < 4; ++m){                          \
        f32x4 bq;                                                             \
        if constexpr (PRE){                                                   \
          bq = *(const f32x4*)&BiasLds[(T)*64 + 32*ct + 8*m + 4*hi];          \
        } else {                                                              \
          const int4 mv = *(const int4*)(MASK + b*2048 + (T)*64 + 32*ct + 8*m + 4*hi); \
          bq[0] = mv.x ? BM_OPEN : BM_MASK;                                   \
          bq[1] = mv.y ? BM_OPEN : BM_MASK;                                   \
          bq[2] = mv.z ? BM_OPEN : BM_MASK;                                   \
          bq[3] = mv.w ? BM_OPEN : BM_MASK;                                   \
        }                                                                     \
        S[ct][4*m+0] = bq[0]; S[ct][4*m+1] = bq[1];                           \
        S[ct][4*m+2] = bq[2]; S[ct][4*m+3] = bq[3];                           \
      }                                                                       \
    }                                                                         \
    __builtin_amdgcn_s_setprio(1);                                            \
    _Pragma("unroll") for (int ct = 0; ct < 2; ++ct){                         \
      _Pragma("unroll") for (int kc = 0; kc < 4; ++kc){                       \
        u16x8 kf = *(const u16x8*)&Kb_[(32*ct + lq)*64 + (((2*kc+hi)^sw7)<<3)]; \
        S[ct] = mfma32(kf, Qf[kc], S[ct]);                                    \
      }                                                                       \
    }                                                                         \
    __builtin_amdgcn_s_setprio(0);                                            \
    u32 pa[2][4], pb[2][4];                                                   \
    float ps = 0.f;                                                           \
    _Pragma("unroll") for (int ct = 0; ct < 2; ++ct){                         \
      _Pragma("unroll") for (int m = 0; m < 4; ++m){                          \
        const float p0 = __builtin_amdgcn_exp2f(S[ct][4*m+0]);                \
        const float p1 = __builtin_amdgcn_exp2f(S[ct][4*m+1]);                \
        const float p2 = __builtin_amdgcn_exp2f(S[ct][4*m+2]);                \
        const float p3 = __builtin_amdgcn_exp2f(S[ct][4*m+3]);                \
        ps += (p0 + p1) + (p2 + p3);                                          \
        pa[ct][m] = cvtpk(p0, p1);                                            \
        pb[ct][m] = cvtpk(p2, p3);                                            \
      }                                                                       \
    }                                                                         \
    lrun += ps;                                                               \
    u16x8 Pf[4];                                                              \
    _Pragma("unroll") for (int ct = 0; ct < 2; ++ct){                         \
      plswap(pa[ct][0], pa[ct][1]);  plswap(pb[ct][0], pb[ct][1]);            \
      plswap(pa[ct][2], pa[ct][3]);  plswap(pb[ct][2], pb[ct][3]);            \
      u32x4 f0_ = { pa[ct][0], pb[ct][0], pa[ct][1], pb[ct][1] };             \
      u32x4 f1_ = { pa[ct][2], pb[ct][2], pa[ct][3], pb[ct][3] };             \
      Pf[2*ct+0] = __builtin_bit_cast(u16x8, f0_);                            \
      Pf[2*ct+1] = __builtin_bit_cast(u16x8, f1_);                            \
    }                                                                         \
    __builtin_amdgcn_s_setprio(1);                                            \
    _Pragma("unroll") for (int dt = 0; dt < 2; ++dt){                         \
      _Pragma("unroll") for (int sc = 0; sc < 4; ++sc){                       \
        u32x4 vv = *(const u32x4*)&vimg_[(32*dt + lq)*32 + (((2*sc+hi)^sw7)<<2)]; \
        Oa[dt] = mfma32(__builtin_bit_cast(u16x8, vv), Pf[sc], Oa[dt]);       \
      }                                                                       \
    }                                                                         \
    __builtin_amdgcn_s_setprio(0);                                            \
  }while(0)

  // ---- prologue ----
  if constexpr (PRE){
    BIAS_STAGE();
    STAGE_ISSUE(t0, &KVbuf[0][0]);
  } else {
    STAGE_REG(0);
    STAGE_WRITE(&KVbuf[0][0]);
  }
  __syncthreads();   // drains DMA (vmcnt) + joins waves

  // ---- main loop: double-buffer, stage t+1 while computing t ----
  for (int tt = 0; tt < NT; ++tt){
    const int t = t0 + tt;
    if (tt < NT-1){
      if constexpr (PRE) STAGE_ISSUE(t+1, &KVbuf[(tt+1) & 1][0]);
      else               STAGE_REG(t+1);
    }
    COMPUTE(t, &KVbuf[tt & 1][0]);
    if (tt < NT-1){
      if constexpr (!PRE) STAGE_WRITE(&KVbuf[(tt+1) & 1][0]);
      __syncthreads();
    }
  }

  // ---- epilogue ----
  {
    float l_ = lrun + __shfl_xor(lrun, 32, 64);
    const int qrow = qbase + lq;
    if constexpr (PRE){
      // write UNNORMALIZED partial O + l (fixed shift => partials sum)
      float* op = OP + (size_t)half*4194304u + q_b + (size_t)qrow*1024 + h*64;
      #pragma unroll
      for (int dt = 0; dt < 2; ++dt){
        #pragma unroll
        for (int m = 0; m < 4; ++m){
          f32x4 ov;
          ov[0] = Oa[dt][4*m+0];
          ov[1] = Oa[dt][4*m+1];
          ov[2] = Oa[dt][4*m+2];
          ov[3] = Oa[dt][4*m+3];
          *(f32x4*)(op + 32*dt + 8*m + 4*hi) = ov;
        }
      }
      if (hi == 0)
        LP[half*65536 + b*32768 + qrow*16 + h] = l_;
    } else {
      const float inv = 1.f / l_;
      float* op = OUT + q_b + (size_t)qrow*1024 + h*64;
      #pragma unroll
      for (int dt = 0; dt < 2; ++dt){
        #pragma unroll
        for (int m = 0; m < 4; ++m){
          f32x4 ov;
          ov[0] = Oa[dt][4*m+0] * inv;
          ov[1] = Oa[dt][4*m+1] * inv;
          ov[2] = Oa[dt][4*m+2] * inv;
          ov[3] = Oa[dt][4*m+3] * inv;
          *(f32x4*)(op + 32*dt + 8*m + 4*hi) = ov;
        }
      }
    }
  }
#undef STAGE_ISSUE
#undef BIAS_STAGE
#undef STAGE_REG
#undef STAGE_WRITE
#undef COMPUTE
}

// ===================== combine: OUT = (O0 + O1) / (l0 + l1) ==================
__global__ __launch_bounds__(256, 8)
void combine(const float* __restrict__ OP, const float* __restrict__ LP,
             float* __restrict__ OUT)
{
  const int gid = blockIdx.x * 256 + threadIdx.x;   // 1048576 threads
  const int elem = gid * 4;
  const int h = (elem >> 6) & 15;
  const int q = (elem >> 10) & 2047;
  const int b = (elem >> 21) & 1;
  f32x4 a = *(const f32x4*)(OP + elem);
  f32x4 c = *(const f32x4*)(OP + 4194304 + elem);
  const int li = b*32768 + q*16 + h;
  const float inv = 1.f / (LP[li] + LP[65536 + li]);
  f32x4 o;
  o[0] = (a[0] + c[0]) * inv;
  o[1] = (a[1] + c[1]) * inv;
  o[2] = (a[2] + c[2]) * inv;
  o[3] = (a[3] + c[3]) * inv;
  *(f32x4*)(OUT + elem) = o;
}

extern "C" void kernel_launch(void* const* d_in, const int* in_sizes, int n_in,
                              void* d_out, int out_size, void* d_ws, size_t ws_size,
                              hipStream_t stream)
{
  const float* Q  = nullptr;
  const float* KV = nullptr;
  const int*   M  = nullptr;
  for (int i = 0; i < n_in; ++i){
    if      (in_sizes[i] == 4194304) Q  = (const float*)d_in[i];
    else if (in_sizes[i] == 8388608) KV = (const float*)d_in[i];
    else if (in_sizes[i] == 4096)    M  = (const int*)d_in[i];
  }
  if (!Q)  Q  = (const float*)d_in[0];
  if (!KV) KV = (const float*)d_in[1];
  if (!M)  M  = (const int*)d_in[2];
  float* O = (float*)d_out;

  // ws: biasm 16KB | img 16.78MB | O-partials 33.55MB | l-partials 512KB
  const size_t NEED = 16384ull + 1024ull*16384ull + 2ull*16777216ull + 524288ull;
  if (ws_size >= NEED){
    float* biasm = (float*)d_ws;
    u16*   img   = (u16*)((char*)d_ws + 16384);
    float* OP    = (float*)((char*)d_ws + 16384 + 16777216);
    float* LP    = OP + 8388608;
    prepass<<<dim3(1024), dim3(256), 0, stream>>>(KV, M, img, biasm);
    attn_main<1><<<dim3(1024), dim3(256), 0, stream>>>(Q, KV, M, img, biasm, OP, LP, O);
    combine<<<dim3(4096), dim3(256), 0, stream>>>(OP, LP, O);
  } else {
    attn_main<0><<<dim3(512), dim3(256), 0, stream>>>(Q, KV, M, nullptr, nullptr,
                                                      nullptr, nullptr, O);
  }
}